// Round 4
// baseline (3009.468 us; speedup 1.0000x reference)
//
#include <hip/hip_runtime.h>
#include <cstdint>

#define BSZ   8
#define TSEQ  2048
#define DMOD  1024
#define NROWS 16384   // B*T
#define NHEAD 16
#define DHEAD 64

// ---------- bf16 helpers ----------
__device__ __forceinline__ float bf2f(unsigned short h) {
  union { unsigned int u; float f; } a; a.u = ((unsigned int)h) << 16; return a.f;
}
__device__ __forceinline__ unsigned short f2bf(float f) {
  union { float f; unsigned int u; } a; a.f = f;
  unsigned int u = a.u;
  u += 0x7fffu + ((u >> 16) & 1u);   // RNE
  return (unsigned short)(u >> 16);
}

typedef __bf16 bf16x8 __attribute__((ext_vector_type(8)));
typedef float  f32x4  __attribute__((ext_vector_type(4)));
typedef float  f32x16 __attribute__((ext_vector_type(16)));

typedef const __attribute__((address_space(1))) void* gas_ptr;
typedef __attribute__((address_space(3))) void*       las_ptr;

__device__ __forceinline__ void gl_lds16(const void* g, void* l) {
  __builtin_amdgcn_global_load_lds((gas_ptr)g, (las_ptr)l, 16, 0, 0);
}

#define BAR()        asm volatile("s_barrier" ::: "memory")
#define WAIT_LGKM(n) asm volatile("s_waitcnt lgkmcnt(" #n ")" ::: "memory")
#define WAIT_VM(n)   asm volatile("s_waitcnt vmcnt(" #n ")" ::: "memory")

// ---------- weight transpose + convert: src (K x N) f32 -> dst (N x K) bf16 ----------
__global__ __launch_bounds__(256) void transpose_cvt(const float* __restrict__ src,
                                                     unsigned short* __restrict__ dst,
                                                     int K, int N) {
  __shared__ float tile[32][33];
  const int n0 = blockIdx.x * 32, k0 = blockIdx.y * 32;
  const int tx = threadIdx.x, ty = threadIdx.y;   // (32, 8)
#pragma unroll
  for (int r = 0; r < 4; ++r)
    tile[ty + r * 8][tx] = src[(size_t)(k0 + ty + r * 8) * N + n0 + tx];
  __syncthreads();
#pragma unroll
  for (int r = 0; r < 4; ++r)
    dst[(size_t)(n0 + ty + r * 8) * K + k0 + tx] = f2bf(tile[tx][ty + r * 8]);
}

__global__ __launch_bounds__(256) void concat_bias(const float* __restrict__ bq,
                                                   const float* __restrict__ bk,
                                                   const float* __restrict__ bv,
                                                   float* __restrict__ out) {
  int i = blockIdx.x * 256 + threadIdx.x;   // 4*3072
  int l = i / 3072, c = i - l * 3072;
  float v;
  if (c < 1024)       v = bq[l * 1024 + c];
  else if (c < 2048)  v = bk[l * 1024 + c - 1024];
  else                v = bv[l * 1024 + c - 2048];
  out[i] = v;
}

// ---------- embed: x = 32*x_in + sinusoidal PE (computed inline) ----------
__global__ __launch_bounds__(256) void embed_k(const float* __restrict__ xin,
                                               float* __restrict__ x) {
  const size_t row = blockIdx.x;
  const int t = blockIdx.x & (TSEQ - 1);
  const int tid = threadIdx.x;
  const int c = tid * 4;
  float4 xv = ((const float4*)(xin + row * DMOD))[tid];
  float o[4];
  float xs[4] = { xv.x, xv.y, xv.z, xv.w };
#pragma unroll
  for (int j = 0; j < 4; ++j) {
    int dd = c + j;
    int i = dd & 511;
    float fr = expf(-0.0180241494559221f * (float)i);  // -ln(10000)/511
    float ang = (float)(t + 1) * fr;
    float pe = (dd < 512) ? sinf(ang) : cosf(ang);
    o[j] = 32.0f * xs[j] + pe;
  }
  float4 ov = { o[0], o[1], o[2], o[3] };
  ((float4*)(x + row * DMOD))[tid] = ov;
}

// ---------- LayerNorm (standalone, used once after embed): fp32 in -> bf16 out ----------
__global__ __launch_bounds__(256) void ln_k(const float* __restrict__ x,
                                            const float* __restrict__ gam,
                                            const float* __restrict__ bet,
                                            unsigned short* __restrict__ outH) {
  const int row = blockIdx.x;
  const int tid = threadIdx.x;
  const float4 xv = ((const float4*)(x + (size_t)row * DMOD))[tid];
  float sum = xv.x + xv.y + xv.z + xv.w;
  float sq  = xv.x * xv.x + xv.y * xv.y + xv.z * xv.z + xv.w * xv.w;
#pragma unroll
  for (int o = 32; o; o >>= 1) { sum += __shfl_xor(sum, o); sq += __shfl_xor(sq, o); }
  __shared__ float s1[4], s2[4];
  const int wid = tid >> 6, lane = tid & 63;
  if (lane == 0) { s1[wid] = sum; s2[wid] = sq; }
  __syncthreads();
  sum = s1[0] + s1[1] + s1[2] + s1[3];
  sq  = s2[0] + s2[1] + s2[2] + s2[3];
  const float mu = sum * (1.0f / 1024.0f);
  const float var = sq * (1.0f / 1024.0f) - mu * mu;
  const float rs = rsqrtf(var + 1e-5f);
  const float4 g = ((const float4*)gam)[tid];
  const float4 b = ((const float4*)bet)[tid];
  union { unsigned short s[4]; uint2 u; } p;
  p.s[0] = f2bf((xv.x - mu) * rs * g.x + b.x);
  p.s[1] = f2bf((xv.y - mu) * rs * g.y + b.y);
  p.s[2] = f2bf((xv.z - mu) * rs * g.z + b.z);
  p.s[3] = f2bf((xv.w - mu) * rs * g.w + b.w);
  ((uint2*)(outH + (size_t)row * DMOD))[tid] = p.u;
}

// ---------- fused residual-add + LayerNorm ----------
template <int FINAL>
__global__ __launch_bounds__(256) void addln_k(float* __restrict__ x,
                                               const unsigned short* y,
                                               const float* __restrict__ gam,
                                               const float* __restrict__ bet,
                                               unsigned short* outH, float* outF) {
  const int row = blockIdx.x;
  const int tid = threadIdx.x;
  float4 xv = ((const float4*)(x + (size_t)row * DMOD))[tid];
  union { uint2 u; unsigned short s[4]; } yv;
  yv.u = ((const uint2*)(y + (size_t)row * DMOD))[tid];
  xv.x += bf2f(yv.s[0]); xv.y += bf2f(yv.s[1]);
  xv.z += bf2f(yv.s[2]); xv.w += bf2f(yv.s[3]);
  float sum = xv.x + xv.y + xv.z + xv.w;
  float sq  = xv.x * xv.x + xv.y * xv.y + xv.z * xv.z + xv.w * xv.w;
#pragma unroll
  for (int o = 32; o; o >>= 1) { sum += __shfl_xor(sum, o); sq += __shfl_xor(sq, o); }
  __shared__ float s1[4], s2[4];
  const int wid = tid >> 6, lane = tid & 63;
  if (lane == 0) { s1[wid] = sum; s2[wid] = sq; }
  __syncthreads();
  sum = s1[0] + s1[1] + s1[2] + s1[3];
  sq  = s2[0] + s2[1] + s2[2] + s2[3];
  const float mu = sum * (1.0f / 1024.0f);
  const float var = sq * (1.0f / 1024.0f) - mu * mu;
  const float rs = rsqrtf(var + 1e-5f);
  const float4 g = ((const float4*)gam)[tid];
  const float4 b = ((const float4*)bet)[tid];
  float o0 = (xv.x - mu) * rs * g.x + b.x;
  float o1 = (xv.y - mu) * rs * g.y + b.y;
  float o2 = (xv.z - mu) * rs * g.z + b.z;
  float o3 = (xv.w - mu) * rs * g.w + b.w;
  if (FINAL) {
    float4 ov = { o0, o1, o2, o3 };
    ((float4*)(outF + (size_t)row * DMOD))[tid] = ov;
  } else {
    ((float4*)(x + (size_t)row * DMOD))[tid] = xv;
    union { unsigned short s[4]; uint2 u; } p;
    p.s[0] = f2bf(o0); p.s[1] = f2bf(o1); p.s[2] = f2bf(o2); p.s[3] = f2bf(o3);
    ((uint2*)(outH + (size_t)row * DMOD))[tid] = p.u;
  }
}

// ---------- GEMM: 256x256 tile, BK=64, 8 waves (2Mx4N), 4-phase/K-tile, 32x32x16 MFMA ----------
// C(MxN,bf16) = A(MxK,bf16,row-stride lda) @ Bt(NxK,bf16)^T + bias, optional RELU.
// Per wave: 128x64 output = 4 mt x 2 nt tiles of 32x32; K-tile = 4 ksteps of 16.
// Quadrants: C1=(a0,b0) C2=(a0,b1) C3=(a1,b0) C4=(a1,b1), a0=mt0-1, a1=mt2-3.
// Reads feed the NEXT cluster (R3 schedule, HW-verified):
//   p1: read b1(T)[4]           lgkm(4)  -> MFMA C1
//   p2: read a1(T)[8]  +stgB0'' lgkm(8)  -> MFMA C2
//   p3: lgkm(0) WAR-guard; stgB1''+A0''; vmcnt(6); BAR(publish T+1); read a0(T+1)[8]; lgkm(8) -> MFMA C3
//   p4: read b0(T+1)[4] +stgA1''                                                             -> MFMA C4
// A/B frag: [m|n = lane&31][k = (lane>>5)*8+j]; C/D: col=lane&31, row=(reg&3)+8*(reg>>2)+4*(lane>>5).
template <int RELU>
__global__ __launch_bounds__(512, 2) void gemm256(const unsigned short* __restrict__ A,
                                                  const unsigned short* __restrict__ Bt,
                                                  const float* __restrict__ bias,
                                                  unsigned short* __restrict__ outH,
                                                  int M, int N, int K, int lda) {
  __shared__ __align__(16) unsigned short sm[65536];   // 128 KB: As dbuf | Bs dbuf; reused as C
  const int tid = threadIdx.x;
  const int wid = tid >> 6, lane = tid & 63;
  const int wm = wid >> 2, wn = wid & 3;               // 2 x 4 wave grid, 128x64 output each

  // bijective XCD swizzle (m204), bm-minor within each XCD chunk for B-panel L2 reuse
  const int nwg = gridDim.x;
  const int qx = nwg >> 3, rx = nwg & 7;
  const int xcd = blockIdx.x & 7, sub = blockIdx.x >> 3;
  const int wg = (xcd < rx ? xcd * (qx + 1) : rx * (qx + 1) + (xcd - rx) * qx) + sub;
  const int nbm = M >> 8;
  const int bm = wg % nbm, bn = wg / nbm;
  const long m0 = (long)bm << 8, n0 = (long)bn << 8;

  // staging: thread t covers row t>>3 of a 64-row group, swizzled 16B chunk (t&7)^(row&7)
  const int srow = tid >> 3;                           // 0..63
  const int cswz = (tid & 7) ^ (srow & 7);
  const unsigned short* Ag = A + (size_t)(m0 + srow) * lda + cswz * 8;
  const unsigned short* Bg = Bt + (size_t)(n0 + srow) * K + cswz * 8;
  char* const smb = (char*)sm;
  const int nT = K >> 6;

#define STAGE_A(t, h)                                                              \
  do {                                                                             \
    const unsigned short* g_ = Ag + (size_t)(t) * 64 + (size_t)((h) * 128) * lda;  \
    char* d_ = smb + (((t) & 1) << 15) + ((h) << 14) + (wid << 10);                \
    gl_lds16(g_, d_);                                                              \
    gl_lds16(g_ + ((size_t)lda << 6), d_ + 8192);                                  \
  } while (0)
#define STAGE_B(t, h)                                                              \
  do {                                                                             \
    const unsigned short* g_ = Bg + (size_t)(t) * 64 + (size_t)((h) * 128) * K;    \
    char* d_ = smb + 65536 + (((t) & 1) << 15) + ((h) << 14) + (wid << 10);        \
    gl_lds16(g_, d_);                                                              \
    gl_lds16(g_ + ((size_t)K << 6), d_ + 8192);                                    \
  } while (0)

  // fragment addressing: row = rowbase + (lane&31); logical 16B chunk c = 2*ks + (lane>>5);
  // physical slot = c ^ (row&7)  -> byte (( (2ks+hi) ^ (lane&7) ) << 4). Loop-invariant per ks.
  const int l31 = lane & 31;
  const int hi  = lane >> 5;
  const int arowb = (wm * 128 + l31) << 7;             // byte offset of lane's A row
  const int browb = (wn * 64  + l31) << 7;
  int coff[4];
#pragma unroll
  for (int ks = 0; ks < 4; ++ks) coff[ks] = (((2 * ks + hi) ^ (lane & 7)) << 4);

  f32x16 acc[4][2] = {};                               // [mt][nt], 128 VGPR
  bf16x8 a0f[2][4], a1f[2][4], b0f[4], b1f[4];

#define READ_A0(buf)                                                               \
  _Pragma("unroll") for (int i = 0; i < 2; ++i)                                    \
  _Pragma("unroll") for (int ks = 0; ks < 4; ++ks)                                 \
    a0f[i][ks] = *(const bf16x8*)((buf) + arowb + i * 4096 + coff[ks]);
#define READ_A1(buf)                                                               \
  _Pragma("unroll") for (int i = 0; i < 2; ++i)                                    \
  _Pragma("unroll") for (int ks = 0; ks < 4; ++ks)                                 \
    a1f[i][ks] = *(const bf16x8*)((buf) + arowb + (i + 2) * 4096 + coff[ks]);
#define READ_B0(buf)                                                               \
  _Pragma("unroll") for (int ks = 0; ks < 4; ++ks)                                 \
    b0f[ks] = *(const bf16x8*)((buf) + browb + coff[ks]);
#define READ_B1(buf)                                                               \
  _Pragma("unroll") for (int ks = 0; ks < 4; ++ks)                                 \
    b1f[ks] = *(const bf16x8*)((buf) + browb + 4096 + coff[ks]);
#define MFMA_Q(accrow, af, bf)                                                     \
  _Pragma("unroll") for (int i = 0; i < 2; ++i)                                    \
  _Pragma("unroll") for (int ks = 0; ks < 4; ++ks)                                 \
    acc[accrow + i][bf##_nt] = __builtin_amdgcn_mfma_f32_32x32x16_bf16(            \
        af[i][ks], bf[ks], acc[accrow + i][bf##_nt], 0, 0, 0);
  const int b0f_nt = 0, b1f_nt = 1;

  // ---- prologue: stage tile0 + tile1; publish tile0; read a0(0), b0(0)
  STAGE_A(0, 0); STAGE_A(0, 1); STAGE_B(0, 0); STAGE_B(0, 1);
  if (nT > 1) {
    STAGE_B(1, 0); STAGE_B(1, 1); STAGE_A(1, 0); STAGE_A(1, 1);
    WAIT_VM(8);
  } else {
    WAIT_VM(0);
  }
  BAR();
  READ_A0(smb);
  READ_B0(smb + 65536);

  for (int T = 0; T < nT; ++T) {
    const char* Ab  = smb + ((T & 1) << 15);
    const char* Bb  = Ab + 65536;
    const char* Ab2 = smb + (((T + 1) & 1) << 15);
    const char* Bb2 = Ab2 + 65536;

    // ---------- p1: read b1(T); MFMA C1 = a0 x b0
    READ_B1(Bb);
    BAR();
    WAIT_LGKM(4);
    __builtin_amdgcn_sched_barrier(0);
    __builtin_amdgcn_s_setprio(1);
    MFMA_Q(0, a0f, b0f);
    __builtin_amdgcn_s_setprio(0);
    __builtin_amdgcn_sched_barrier(0);
    BAR();

    // ---------- p2: read a1(T); stage B(T+2,h0); MFMA C2 = a0 x b1
    READ_A1(Ab);
    if (T + 2 < nT) STAGE_B(T + 2, 0);
    BAR();
    WAIT_LGKM(8);
    __builtin_amdgcn_sched_barrier(0);
    __builtin_amdgcn_s_setprio(1);
    MFMA_Q(0, a0f, b1f);
    __builtin_amdgcn_s_setprio(0);
    __builtin_amdgcn_sched_barrier(0);
    BAR();

    // ---------- p3: WAR-guard (a1 complete); stage B(T+2,h1)+A(T+2,h0); vmcnt;
    //             BAR publishes tile T+1; read a0(T+1); MFMA C3 = a1 x b0
    WAIT_LGKM(0);
    if (T + 2 < nT) {
      STAGE_B(T + 2, 1); STAGE_A(T + 2, 0);
      WAIT_VM(6);                       // all of tile T+1 landed; 6 newest (T+2 pieces) in flight
    } else if (T + 1 < nT) {
      WAIT_VM(0);                       // tail: drain tile T+1
    }
    BAR();
    if (T + 1 < nT) {
      READ_A0(Ab2);
      WAIT_LGKM(8);                     // a0' may stay outstanding (consumed next tile @p1 lgkm(4))
    } else {
      WAIT_LGKM(0);
    }
    __builtin_amdgcn_sched_barrier(0);
    __builtin_amdgcn_s_setprio(1);
    MFMA_Q(2, a1f, b0f);
    __builtin_amdgcn_s_setprio(0);
    __builtin_amdgcn_sched_barrier(0);
    BAR();

    // ---------- p4: read b0(T+1); stage A(T+2,h1); MFMA C4 = a1 x b1 (operands already waited)
    if (T + 1 < nT) {
      READ_B0(Bb2);
    }
    if (T + 2 < nT) STAGE_A(T + 2, 1);
    BAR();
    __builtin_amdgcn_sched_barrier(0);
    __builtin_amdgcn_s_setprio(1);
    MFMA_Q(2, a1f, b1f);
    __builtin_amdgcn_s_setprio(0);
    __builtin_amdgcn_sched_barrier(0);
    BAR();
  }
#undef STAGE_A
#undef STAGE_B
#undef READ_A0
#undef READ_A1
#undef READ_B0
#undef READ_B1
#undef MFMA_Q

  // ---- epilogue: drain all gl_lds before reusing LDS as C tile (256x256 bf16 = 128 KB)
  WAIT_VM(0);
  __syncthreads();
#pragma unroll
  for (int nt = 0; nt < 2; ++nt) {
    const int col = wn * 64 + nt * 32 + l31;
    const float bb = bias[n0 + col];
#pragma unroll
    for (int mt = 0; mt < 4; ++mt) {
#pragma unroll
      for (int rr = 0; rr < 16; ++rr) {
        const int row = wm * 128 + mt * 32 + (rr & 3) + 8 * (rr >> 2) + 4 * hi;
        float val = acc[mt][nt][rr] + bb;
        if (RELU) val = fmaxf(val, 0.0f);
        sm[row * 256 + (col ^ ((row & 12) << 2))] = f2bf(val);
      }
    }
  }
  __syncthreads();
#pragma unroll
  for (int it = 0; it < 16; ++it) {
    const int row = it * 16 + (tid >> 5);
    const int ch = tid & 31;
    const int chs = ch ^ ((row & 12) >> 1);
    const uint4 val = *(const uint4*)(sm + row * 256 + chs * 8);
    *(uint4*)(outH + (size_t)(m0 + row) * N + n0 + ch * 8) = val;
  }
}

// ---------- linear attention ----------
__global__ __launch_bounds__(256) void attn_kv_partial(const unsigned short* __restrict__ qkv,
                                                       float* __restrict__ kvp,
                                                       float* __restrict__ ksump) {
  const int bh = blockIdx.x, tc = blockIdx.y;
  const int b = bh >> 4, h = bh & 15;
  const int tid = threadIdx.x;
  const int m = tid & 63, wid = tid >> 6;
  __shared__ float ks[32][64];
  __shared__ float vs[32][64];
  float acc[16];
#pragma unroll
  for (int j = 0; j < 16; ++j) acc[j] = 0.0f;
  float ksacc = 0.0f;
  const int tt = tid >> 3;
  const int dsb = (tid & 7) * 8;
  const size_t base = ((size_t)b * TSEQ + tc * 256) * 3072;
  const int kcol = 1024 + h * 64 + dsb, vcol = 2048 + h * 64 + dsb;
  for (int sc = 0; sc < 8; ++sc) {
    __syncthreads();
    const size_t roff = base + (size_t)(sc * 32 + tt) * 3072;
    uint4 kb = *(const uint4*)(qkv + roff + kcol);
    uint4 vb = *(const uint4*)(qkv + roff + vcol);
    const unsigned int* kw = (const unsigned int*)&kb;
    const unsigned int* vw = (const unsigned int*)&vb;
#pragma unroll
    for (int w2 = 0; w2 < 4; ++w2) {
      float k0 = bf2f((unsigned short)(kw[w2] & 0xffffu));
      float k1 = bf2f((unsigned short)(kw[w2] >> 16));
      ks[tt][dsb + 2 * w2]     = (k0 > 0.f) ? k0 + 1.f : expf(k0);  // elu(k)+1
      ks[tt][dsb + 2 * w2 + 1] = (k1 > 0.f) ? k1 + 1.f : expf(k1);
      vs[tt][dsb + 2 * w2]     = bf2f((unsigned short)(vw[w2] & 0xffffu));
      vs[tt][dsb + 2 * w2 + 1] = bf2f((unsigned short)(vw[w2] >> 16));
    }
    __syncthreads();
#pragma unroll 4
    for (int t2 = 0; t2 < 32; ++t2) {
      float vv = vs[t2][m];
#pragma unroll
      for (int j = 0; j < 16; ++j) acc[j] += ks[t2][wid * 16 + j] * vv;  // broadcast read
      if (tid < 64) ksacc += ks[t2][tid];
    }
  }
  float* dst = kvp + (size_t)(tc * 128 + bh) * 4096;
#pragma unroll
  for (int j = 0; j < 16; ++j) dst[(wid * 16 + j) * 64 + m] = acc[j];
  if (tid < 64) ksump[(size_t)(tc * 128 + bh) * 64 + tid] = ksacc;
}

__global__ __launch_bounds__(256) void attn_kv_reduce(const float* __restrict__ kvp,
                                                      const float* __restrict__ ksump,
                                                      float* __restrict__ kvf,
                                                      float* __restrict__ ksumf) {
  const int bh = blockIdx.x;
  const int tid = threadIdx.x;
  for (int i = tid; i < 4096; i += 256) {
    float s = 0.f;
#pragma unroll
    for (int tc = 0; tc < 8; ++tc) s += kvp[(size_t)(tc * 128 + bh) * 4096 + i];
    kvf[(size_t)bh * 4096 + i] = s;
  }
  if (tid < 64) {
    float s = 0.f;
#pragma unroll
    for (int tc = 0; tc < 8; ++tc) s += ksump[(size_t)(tc * 128 + bh) * 64 + tid];
    ksumf[bh * 64 + tid] = s;
  }
}

// phase B: out[t,m] = (sum_d qp[d]*kv[d][m]) / (qp . ksum + eps); 4 t-rows per pass
__global__ __launch_bounds__(256) void attn_out_k(const unsigned short* __restrict__ qkv,
                                                  const float* __restrict__ kvf,
                                                  const float* __restrict__ ksumf,
                                                  unsigned short* __restrict__ qkvO) {
  const int bh = blockIdx.x, tcb = blockIdx.y;
  const int b = bh >> 4, h = bh & 15;
  const int tid = threadIdx.x, wid = tid >> 6, lane = tid & 63;
  __shared__ float kvs[4096];
  __shared__ float kss[64];
  __shared__ float qps[4][4][64];
  for (int i = tid; i < 1024; i += 256)
    ((float4*)kvs)[i] = ((const float4*)(kvf + (size_t)bh * 4096))[i];
  if (tid < 64) kss[tid] = ksumf[bh * 64 + tid];
  __syncthreads();
  for (int it = 0; it < 64; it += 4) {
    float zr[4];
#pragma unroll
    for (int r = 0; r < 4; ++r) {
      const int t = tcb * 256 + wid * 64 + it + r;
      const size_t row = (size_t)b * TSEQ + t;
      float qv = bf2f(qkv[row * 3072 + h * 64 + lane]);
      float qp = (qv > 0.f) ? qv + 1.f : expf(qv);
      float rs = qp * kss[lane];
#pragma unroll
      for (int o = 32; o; o >>= 1) rs += __shfl_xor(rs, o);
      zr[r] = 1.0f / (rs + 1e-6f);
      qps[wid][r][lane] = qp;
    }
    float o0 = 0.f, o1 = 0.f, o2 = 0.f, o3 = 0.f;
#pragma unroll 8
    for (int d = 0; d < 64; ++d) {
      const float kvv = kvs[d * 64 + lane];
      o0 += qps[wid][0][d] * kvv;
      o1 += qps[wid][1][d] * kvv;
      o2 += qps[wid][2][d] * kvv;
      o3 += qps[wid][3][d] * kvv;
    }
    const size_t row0 = (size_t)b * TSEQ + tcb * 256 + wid * 64 + it;
    qkvO[(row0 + 0) * 3072 + h * 64 + lane] = f2bf(o0 * zr[0]);
    qkvO[(row0 + 1) * 3072 + h * 64 + lane] = f2bf(o1 * zr[1]);
    qkvO[(row0 + 2) * 3072 + h * 64 + lane] = f2bf(o2 * zr[2]);
    qkvO[(row0 + 3) * 3072 + h * 64 + lane] = f2bf(o3 * zr[3]);
  }
}

// ---------- launch ----------
extern "C" void kernel_launch(void* const* d_in, const int* in_sizes, int n_in,
                              void* d_out, int out_size, void* d_ws, size_t ws_size,
                              hipStream_t stream) {
  const float* x_in = (const float*)d_in[0];
  const float* Wq = (const float*)d_in[1];
  const float* bq = (const float*)d_in[2];
  const float* Wk = (const float*)d_in[3];
  const float* bk = (const float*)d_in[4];
  const float* Wv = (const float*)d_in[5];
  const float* bv = (const float*)d_in[6];
  const float* Wo = (const float*)d_in[7];
  const float* bo = (const float*)d_in[8];
  const float* W1 = (const float*)d_in[9];
  const float* b1 = (const float*)d_in[10];
  const float* W2 = (const float*)d_in[11];
  const float* b2 = (const float*)d_in[12];
  const float* ln1s = (const float*)d_in[13];
  const float* ln1b = (const float*)d_in[14];
  const float* ln2s = (const float*)d_in[15];
  const float* ln2b = (const float*)d_in[16];
  const float* lnfs = (const float*)d_in[17];
  const float* lnfb = (const float*)d_in[18];

  // Residual x lives in d_out (NROWS*DMOD f32); final addln<1> writes LN result in-place.
  float* x = (float*)d_out;

  // Workspace layout (~202.3 MiB):
  char* w = (char*)d_ws;
  unsigned short* hh    = (unsigned short*)(w + 0);           //  32 MB bf16 LN out / y
  unsigned short* qkv   = (unsigned short*)(w + 33554432);    //  96 MB bf16 q|k|v
  unsigned short* h1    = (unsigned short*)(w + 33554432);    // 128 MB bf16 FFN mid (aliases qkv)
  unsigned short* qkvwt = (unsigned short*)(w + 167772160);   //   6 MB per-layer Wqkv^T
  unsigned short* wot   = (unsigned short*)(w + 174063616);   //   2 MB per-layer Wo^T
  unsigned short* w1t   = (unsigned short*)(w + 176160768);   //   8 MB per-layer W1^T
  unsigned short* w2t   = (unsigned short*)(w + 184549376);   //   8 MB per-layer W2^T
  float*          bqkv  = (float*)(w + 192937984);            //  48 KB
  float*          kvp   = (float*)(w + 192987136);            //  16 MB
  float*          ksump = (float*)(w + 209764352);            // 256 KB
  float*          kvf   = (float*)(w + 210026496);            //   2 MB
  float*          ksumf = (float*)(w + 212123648);            //  32 KB
  (void)ws_size; (void)in_sizes; (void)n_in; (void)out_size;

  dim3 b256(256);
  dim3 b512(512);
  dim3 tb(32, 8);
  concat_bias<<<48, b256, 0, stream>>>(bq, bk, bv, bqkv);
  embed_k<<<NROWS, b256, 0, stream>>>(x_in, x);
  ln_k<<<NROWS, b256, 0, stream>>>(x, ln1s, ln1b, hh);

  for (int l = 0; l < 4; ++l) {
    transpose_cvt<<<dim3(32, 32), tb, 0, stream>>>(Wq + (size_t)l * 1048576, qkvwt,           1024, 1024);
    transpose_cvt<<<dim3(32, 32), tb, 0, stream>>>(Wk + (size_t)l * 1048576, qkvwt + 1048576, 1024, 1024);
    transpose_cvt<<<dim3(32, 32), tb, 0, stream>>>(Wv + (size_t)l * 1048576, qkvwt + 2097152, 1024, 1024);
    transpose_cvt<<<dim3(32, 32), tb, 0, stream>>>(Wo + (size_t)l * 1048576, wot, 1024, 1024);
    transpose_cvt<<<dim3(128, 32), tb, 0, stream>>>(W1 + (size_t)l * 4194304, w1t, 1024, 4096);
    transpose_cvt<<<dim3(32, 128), tb, 0, stream>>>(W2 + (size_t)l * 4194304, w2t, 4096, 1024);

    // QKV projection (reads hh = LN1 output)
    gemm256<0><<<dim3(64 * 12), b512, 0, stream>>>(hh, qkvwt, bqkv + l * 3072, qkv,
                                                   NROWS, 3072, 1024, 1024);
    attn_kv_partial<<<dim3(128, 8), b256, 0, stream>>>(qkv, kvp, ksump);
    attn_kv_reduce<<<128, b256, 0, stream>>>(kvp, ksump, kvf, ksumf);
    attn_out_k<<<dim3(128, 8), b256, 0, stream>>>(qkv, kvf, ksumf, qkv);
    // Wo: A = attn output in q-slice of qkv (lda 3072); y -> hh (dead after QKV gemm)
    gemm256<0><<<dim3(64 * 4), b512, 0, stream>>>(qkv, wot, bo + l * 1024, hh,
                                                  NROWS, 1024, 1024, 3072);
    addln_k<0><<<NROWS, b256, 0, stream>>>(x, hh, ln2s + l * 1024, ln2b + l * 1024, hh, nullptr);
    // FFN
    gemm256<1><<<dim3(64 * 16), b512, 0, stream>>>(hh, w1t, b1 + l * 4096, h1,
                                                   NROWS, 4096, 1024, 1024);
    gemm256<0><<<dim3(64 * 4), b512, 0, stream>>>(h1, w2t, b2 + l * 1024, hh,
                                                  NROWS, 1024, 4096, 4096);
    if (l < 3)
      addln_k<0><<<NROWS, b256, 0, stream>>>(x, hh, ln1s + (l + 1) * 1024, ln1b + (l + 1) * 1024,
                                             hh, nullptr);
    else
      addln_k<1><<<NROWS, b256, 0, stream>>>(x, hh, lnfs, lnfb, nullptr, x);
  }
}

// Round 5
// 2777.228 us; speedup vs baseline: 1.0836x; 1.0836x over previous
//
#include <hip/hip_runtime.h>
#include <cstdint>

#define BSZ   8
#define TSEQ  2048
#define DMOD  1024
#define NROWS 16384   // B*T
#define NHEAD 16
#define DHEAD 64

// ---------- bf16 helpers ----------
__device__ __forceinline__ float bf2f(unsigned short h) {
  union { unsigned int u; float f; } a; a.u = ((unsigned int)h) << 16; return a.f;
}
__device__ __forceinline__ unsigned short f2bf(float f) {
  union { float f; unsigned int u; } a; a.f = f;
  unsigned int u = a.u;
  u += 0x7fffu + ((u >> 16) & 1u);   // RNE
  return (unsigned short)(u >> 16);
}

typedef __bf16 bf16x8 __attribute__((ext_vector_type(8)));
typedef float  f32x4  __attribute__((ext_vector_type(4)));

typedef const __attribute__((address_space(1))) void* gas_ptr;
typedef __attribute__((address_space(3))) void*       las_ptr;

__device__ __forceinline__ void gl_lds16(const void* g, void* l) {
  __builtin_amdgcn_global_load_lds((gas_ptr)g, (las_ptr)l, 16, 0, 0);
}

#define BAR()        asm volatile("s_barrier" ::: "memory")
#define WAIT_LGKM(n) asm volatile("s_waitcnt lgkmcnt(" #n ")" ::: "memory")
#define WAIT_VM(n)   asm volatile("s_waitcnt vmcnt(" #n ")" ::: "memory")

// ---------- weight transpose + convert: src (K x N) f32 -> dst (N x K) bf16 ----------
__global__ __launch_bounds__(256) void transpose_cvt(const float* __restrict__ src,
                                                     unsigned short* __restrict__ dst,
                                                     int K, int N) {
  __shared__ float tile[32][33];
  const int n0 = blockIdx.x * 32, k0 = blockIdx.y * 32;
  const int tx = threadIdx.x, ty = threadIdx.y;   // (32, 8)
#pragma unroll
  for (int r = 0; r < 4; ++r)
    tile[ty + r * 8][tx] = src[(size_t)(k0 + ty + r * 8) * N + n0 + tx];
  __syncthreads();
#pragma unroll
  for (int r = 0; r < 4; ++r)
    dst[(size_t)(n0 + ty + r * 8) * K + k0 + tx] = f2bf(tile[tx][ty + r * 8]);
}

__global__ __launch_bounds__(256) void concat_bias(const float* __restrict__ bq,
                                                   const float* __restrict__ bk,
                                                   const float* __restrict__ bv,
                                                   float* __restrict__ out) {
  int i = blockIdx.x * 256 + threadIdx.x;   // 4*3072
  int l = i / 3072, c = i - l * 3072;
  float v;
  if (c < 1024)       v = bq[l * 1024 + c];
  else if (c < 2048)  v = bk[l * 1024 + c - 1024];
  else                v = bv[l * 1024 + c - 2048];
  out[i] = v;
}

// ---------- fused embed + LayerNorm: x = 32*x_in + PE; hh = LN(x) ----------
// Replaces embed_k + ln_k: saves one full 64 MB re-read of x and one launch.
// Arithmetic order identical to the split version (x round-trips f32 exactly).
__global__ __launch_bounds__(256) void embedln_k(const float* __restrict__ xin,
                                                 const float* __restrict__ gam,
                                                 const float* __restrict__ bet,
                                                 float* __restrict__ x,
                                                 unsigned short* __restrict__ outH) {
  const size_t row = blockIdx.x;
  const int t = blockIdx.x & (TSEQ - 1);
  const int tid = threadIdx.x;
  const int c = tid * 4;
  float4 xv = ((const float4*)(xin + row * DMOD))[tid];
  float o[4];
  float xs[4] = { xv.x, xv.y, xv.z, xv.w };
#pragma unroll
  for (int j = 0; j < 4; ++j) {
    int dd = c + j;
    int i = dd & 511;
    float fr = expf(-0.0180241494559221f * (float)i);  // -ln(10000)/511
    float ang = (float)(t + 1) * fr;
    float pe = (dd < 512) ? sinf(ang) : cosf(ang);
    o[j] = 32.0f * xs[j] + pe;
  }
  float4 ov = { o[0], o[1], o[2], o[3] };
  ((float4*)(x + row * DMOD))[tid] = ov;

  float sum = o[0] + o[1] + o[2] + o[3];
  float sq  = o[0] * o[0] + o[1] * o[1] + o[2] * o[2] + o[3] * o[3];
#pragma unroll
  for (int of = 32; of; of >>= 1) { sum += __shfl_xor(sum, of); sq += __shfl_xor(sq, of); }
  __shared__ float s1[4], s2[4];
  const int wid = tid >> 6, lane = tid & 63;
  if (lane == 0) { s1[wid] = sum; s2[wid] = sq; }
  __syncthreads();
  sum = s1[0] + s1[1] + s1[2] + s1[3];
  sq  = s2[0] + s2[1] + s2[2] + s2[3];
  const float mu = sum * (1.0f / 1024.0f);
  const float var = sq * (1.0f / 1024.0f) - mu * mu;
  const float rs = rsqrtf(var + 1e-5f);
  const float4 g = ((const float4*)gam)[tid];
  const float4 b = ((const float4*)bet)[tid];
  union { unsigned short s[4]; uint2 u; } p;
  p.s[0] = f2bf((o[0] - mu) * rs * g.x + b.x);
  p.s[1] = f2bf((o[1] - mu) * rs * g.y + b.y);
  p.s[2] = f2bf((o[2] - mu) * rs * g.z + b.z);
  p.s[3] = f2bf((o[3] - mu) * rs * g.w + b.w);
  ((uint2*)(outH + row * DMOD))[tid] = p.u;
}

// ---------- fused residual-add + LayerNorm ----------
template <int FINAL>
__global__ __launch_bounds__(256) void addln_k(float* __restrict__ x,
                                               const unsigned short* y,
                                               const float* __restrict__ gam,
                                               const float* __restrict__ bet,
                                               unsigned short* outH, float* outF) {
  const int row = blockIdx.x;
  const int tid = threadIdx.x;
  float4 xv = ((const float4*)(x + (size_t)row * DMOD))[tid];
  union { uint2 u; unsigned short s[4]; } yv;
  yv.u = ((const uint2*)(y + (size_t)row * DMOD))[tid];
  xv.x += bf2f(yv.s[0]); xv.y += bf2f(yv.s[1]);
  xv.z += bf2f(yv.s[2]); xv.w += bf2f(yv.s[3]);
  float sum = xv.x + xv.y + xv.z + xv.w;
  float sq  = xv.x * xv.x + xv.y * xv.y + xv.z * xv.z + xv.w * xv.w;
#pragma unroll
  for (int o = 32; o; o >>= 1) { sum += __shfl_xor(sum, o); sq += __shfl_xor(sq, o); }
  __shared__ float s1[4], s2[4];
  const int wid = tid >> 6, lane = tid & 63;
  if (lane == 0) { s1[wid] = sum; s2[wid] = sq; }
  __syncthreads();
  sum = s1[0] + s1[1] + s1[2] + s1[3];
  sq  = s2[0] + s2[1] + s2[2] + s2[3];
  const float mu = sum * (1.0f / 1024.0f);
  const float var = sq * (1.0f / 1024.0f) - mu * mu;
  const float rs = rsqrtf(var + 1e-5f);
  const float4 g = ((const float4*)gam)[tid];
  const float4 b = ((const float4*)bet)[tid];
  float o0 = (xv.x - mu) * rs * g.x + b.x;
  float o1 = (xv.y - mu) * rs * g.y + b.y;
  float o2 = (xv.z - mu) * rs * g.z + b.z;
  float o3 = (xv.w - mu) * rs * g.w + b.w;
  if (FINAL) {
    float4 ov = { o0, o1, o2, o3 };
    ((float4*)(outF + (size_t)row * DMOD))[tid] = ov;
  } else {
    ((float4*)(x + (size_t)row * DMOD))[tid] = xv;
    union { unsigned short s[4]; uint2 u; } p;
    p.s[0] = f2bf(o0); p.s[1] = f2bf(o1); p.s[2] = f2bf(o2); p.s[3] = f2bf(o3);
    ((uint2*)(outH + (size_t)row * DMOD))[tid] = p.u;
  }
}

// ---------- GEMM: 256x256 tile, BK=64, 8 waves (2Mx4N), 4-phase/K-tile, one-phase-ahead reads ----------
// (R3 kernel verbatim — harness-verified: 165 us W1-class, MfmaUtil ~35%, 0 bank conflicts.
//  At the m248-measured plain-HIP ceiling (~850 TF) for 256²/K=1024-class shapes at 1 block/CU;
//  occupancy is register-bound: acc 128 AGPR + 128 VGPR = 256 regs/wave -> 8 waves/CU.)
template <int RELU>
__global__ __launch_bounds__(512, 2) void gemm256(const unsigned short* __restrict__ A,
                                                  const unsigned short* __restrict__ Bt,
                                                  const float* __restrict__ bias,
                                                  unsigned short* __restrict__ outH,
                                                  int M, int N, int K, int lda) {
  __shared__ __align__(16) unsigned short sm[65536];   // 128 KB: As dbuf | Bs dbuf; reused as C
  const int tid = threadIdx.x;
  const int wid = tid >> 6, lane = tid & 63;
  const int wm = wid >> 2, wn = wid & 3;               // 2 x 4 wave grid, 128x64 output each

  // bijective XCD swizzle (m204), bm-minor within each XCD chunk for B-panel L2 reuse
  const int nwg = gridDim.x;
  const int q = nwg >> 3, r = nwg & 7;
  const int xcd = blockIdx.x & 7, sub = blockIdx.x >> 3;
  const int wg = (xcd < r ? xcd * (q + 1) : r * (q + 1) + (xcd - r) * q) + sub;
  const int nbm = M >> 8;
  const int bm = wg % nbm, bn = wg / nbm;
  const long m0 = (long)bm << 8, n0 = (long)bn << 8;

  // staging: thread t covers row t>>3 of a 64-row group, swizzled 16B chunk (t&7)^(row&7)
  const int srow = tid >> 3;                           // 0..63
  const int cswz = (tid & 7) ^ (srow & 7);
  const unsigned short* Ag = A + (size_t)(m0 + srow) * lda + cswz * 8;
  const unsigned short* Bg = Bt + (size_t)(n0 + srow) * K + cswz * 8;
  char* const smb = (char*)sm;
  const int nT = K >> 6;

#define STAGE_A(t, h)                                                              \
  do {                                                                             \
    const unsigned short* g_ = Ag + (size_t)(t) * 64 + (size_t)((h) * 128) * lda;  \
    char* d_ = smb + (((t) & 1) << 15) + ((h) << 14) + (wid << 10);                \
    gl_lds16(g_, d_);                                                              \
    gl_lds16(g_ + ((size_t)lda << 6), d_ + 8192);                                  \
  } while (0)
#define STAGE_B(t, h)                                                              \
  do {                                                                             \
    const unsigned short* g_ = Bg + (size_t)(t) * 64 + (size_t)((h) * 128) * K;    \
    char* d_ = smb + 65536 + (((t) & 1) << 15) + ((h) << 14) + (wid << 10);        \
    gl_lds16(g_, d_);                                                              \
    gl_lds16(g_ + ((size_t)K << 6), d_ + 8192);                                    \
  } while (0)

  // fragment reads: row = tilebase + (lane&15); chunk (lane>>4)+4*ks at slot chunk^(row&7)
  const int fr = lane & 15;
  const int aswz = ((lane >> 4) ^ (lane & 7)) << 4;
  const int aoff = (wm * 128 + fr) * 128;              // byte row offset in A buffer
  const int boff = (wn * 64 + fr) * 128;

  f32x4 acc[8][4] = {};
  bf16x8 a0[4][2], a1[4][2], b01[2][2], b23[2][2];

  // ---- prologue: stage tile0 + tile1; publish tile0; read a0(0), b01(0)
  STAGE_A(0, 0); STAGE_A(0, 1); STAGE_B(0, 0); STAGE_B(0, 1);
  if (nT > 1) {
    STAGE_B(1, 0); STAGE_B(1, 1); STAGE_A(1, 0); STAGE_A(1, 1);
    WAIT_VM(8);
  } else {
    WAIT_VM(0);
  }
  BAR();
#pragma unroll
  for (int i = 0; i < 4; ++i)
#pragma unroll
    for (int ks = 0; ks < 2; ++ks)
      a0[i][ks] = *(const bf16x8*)(smb + aoff + i * 2048 + (aswz ^ (ks << 6)));
#pragma unroll
  for (int j = 0; j < 2; ++j)
#pragma unroll
    for (int ks = 0; ks < 2; ++ks)
      b01[j][ks] = *(const bf16x8*)(smb + 65536 + boff + j * 2048 + (aswz ^ (ks << 6)));

  for (int T = 0; T < nT; ++T) {
    const char* Ab  = smb + ((T & 1) << 15);
    const char* Bb  = Ab + 65536;
    const char* Ab2 = smb + (((T + 1) & 1) << 15);
    const char* Bb2 = Ab2 + 65536;

    // ---------- p1: read b23(T); MFMA C1 = a0 x b01
#pragma unroll
    for (int j = 0; j < 2; ++j)
#pragma unroll
      for (int ks = 0; ks < 2; ++ks)
        b23[j][ks] = *(const bf16x8*)(Bb + boff + (j + 2) * 2048 + (aswz ^ (ks << 6)));
    BAR();
    WAIT_LGKM(4);
    __builtin_amdgcn_sched_barrier(0);
    __builtin_amdgcn_s_setprio(1);
#pragma unroll
    for (int i = 0; i < 4; ++i)
#pragma unroll
      for (int j = 0; j < 2; ++j)
#pragma unroll
        for (int ks = 0; ks < 2; ++ks)
          acc[i][j] = __builtin_amdgcn_mfma_f32_16x16x32_bf16(a0[i][ks], b01[j][ks], acc[i][j], 0, 0, 0);
    __builtin_amdgcn_s_setprio(0);
    __builtin_amdgcn_sched_barrier(0);
    BAR();

    // ---------- p2: read a1(T); stage B(T+2,h0); MFMA C2 = a0 x b23
#pragma unroll
    for (int i = 0; i < 4; ++i)
#pragma unroll
      for (int ks = 0; ks < 2; ++ks)
        a1[i][ks] = *(const bf16x8*)(Ab + aoff + (i + 4) * 2048 + (aswz ^ (ks << 6)));
    if (T + 2 < nT) STAGE_B(T + 2, 0);
    BAR();
    WAIT_LGKM(8);
    __builtin_amdgcn_sched_barrier(0);
    __builtin_amdgcn_s_setprio(1);
#pragma unroll
    for (int i = 0; i < 4; ++i)
#pragma unroll
      for (int j = 0; j < 2; ++j)
#pragma unroll
        for (int ks = 0; ks < 2; ++ks)
          acc[i][j + 2] = __builtin_amdgcn_mfma_f32_16x16x32_bf16(a0[i][ks], b23[j][ks], acc[i][j + 2], 0, 0, 0);
    __builtin_amdgcn_s_setprio(0);
    __builtin_amdgcn_sched_barrier(0);
    BAR();

    // ---------- p3: WAR-guard (a1 reads complete, ~free: issued a full phase ago);
    //             stage B(T+2,h1)+A(T+2,h0); vmcnt; BAR publishes tile T+1; read a0(T+1); MFMA C3
    WAIT_LGKM(0);
    if (T + 2 < nT) {
      STAGE_B(T + 2, 1); STAGE_A(T + 2, 0);
      WAIT_VM(6);                       // all of tile T+1 landed; 6 newest (T+2 pieces) in flight
    } else if (T + 1 < nT) {
      WAIT_VM(0);                       // tail: drain tile T+1
    }
    BAR();
    if (T + 1 < nT) {
#pragma unroll
      for (int i = 0; i < 4; ++i)
#pragma unroll
        for (int ks = 0; ks < 2; ++ks)
          a0[i][ks] = *(const bf16x8*)(Ab2 + aoff + i * 2048 + (aswz ^ (ks << 6)));
      WAIT_LGKM(8);                     // a0' may stay outstanding (consumed next tile @p1 lgkm(4))
    } else {
      WAIT_LGKM(0);
    }
    __builtin_amdgcn_sched_barrier(0);
    __builtin_amdgcn_s_setprio(1);
#pragma unroll
    for (int i = 0; i < 4; ++i)
#pragma unroll
      for (int j = 0; j < 2; ++j)
#pragma unroll
        for (int ks = 0; ks < 2; ++ks)
          acc[i + 4][j] = __builtin_amdgcn_mfma_f32_16x16x32_bf16(a1[i][ks], b01[j][ks], acc[i + 4][j], 0, 0, 0);
    __builtin_amdgcn_s_setprio(0);
    __builtin_amdgcn_sched_barrier(0);
    BAR();

    // ---------- p4: read b01(T+1); stage A(T+2,h1); MFMA C4 = a1 x b23 (operands already waited)
    if (T + 1 < nT) {
#pragma unroll
      for (int j = 0; j < 2; ++j)
#pragma unroll
        for (int ks = 0; ks < 2; ++ks)
          b01[j][ks] = *(const bf16x8*)(Bb2 + boff + j * 2048 + (aswz ^ (ks << 6)));
    }
    if (T + 2 < nT) STAGE_A(T + 2, 1);
    BAR();
    __builtin_amdgcn_sched_barrier(0);
    __builtin_amdgcn_s_setprio(1);
#pragma unroll
    for (int i = 0; i < 4; ++i)
#pragma unroll
      for (int j = 0; j < 2; ++j)
#pragma unroll
        for (int ks = 0; ks < 2; ++ks)
          acc[i + 4][j + 2] = __builtin_amdgcn_mfma_f32_16x16x32_bf16(a1[i][ks], b23[j][ks], acc[i + 4][j + 2], 0, 0, 0);
    __builtin_amdgcn_s_setprio(0);
    __builtin_amdgcn_sched_barrier(0);
    BAR();
  }
#undef STAGE_A
#undef STAGE_B

  // ---- epilogue: drain all gl_lds before reusing LDS as C tile (256x256 bf16 = 128 KB)
  WAIT_VM(0);
  __syncthreads();
  {
    const int cq = lane >> 4, cn = lane & 15;
#pragma unroll
    for (int j = 0; j < 4; ++j) {
      const float bb = bias[n0 + wn * 64 + j * 16 + cn];
#pragma unroll
      for (int i = 0; i < 8; ++i)
#pragma unroll
        for (int v = 0; v < 4; ++v) {
          const int row = wm * 128 + i * 16 + cq * 4 + v;
          const int col = wn * 64 + j * 16 + cn;
          float val = acc[i][j][v] + bb;
          if (RELU) val = fmaxf(val, 0.0f);
          sm[row * 256 + (col ^ ((row & 12) << 2))] = f2bf(val);
        }
    }
  }
  __syncthreads();
#pragma unroll
  for (int it = 0; it < 16; ++it) {
    const int row = it * 16 + (tid >> 5);
    const int ch = tid & 31;
    const int chs = ch ^ ((row & 12) >> 1);
    const uint4 val = *(const uint4*)(sm + row * 256 + chs * 8);
    *(uint4*)(outH + (size_t)(m0 + row) * N + n0 + ch * 8) = val;
  }
}

// ---------- linear attention ----------
__global__ __launch_bounds__(256) void attn_kv_partial(const unsigned short* __restrict__ qkv,
                                                       float* __restrict__ kvp,
                                                       float* __restrict__ ksump) {
  const int bh = blockIdx.x, tc = blockIdx.y;
  const int b = bh >> 4, h = bh & 15;
  const int tid = threadIdx.x;
  const int m = tid & 63, wid = tid >> 6;
  __shared__ float ks[32][64];
  __shared__ float vs[32][64];
  float acc[16];
#pragma unroll
  for (int j = 0; j < 16; ++j) acc[j] = 0.0f;
  float ksacc = 0.0f;
  const int tt = tid >> 3;
  const int dsb = (tid & 7) * 8;
  const size_t base = ((size_t)b * TSEQ + tc * 256) * 3072;
  const int kcol = 1024 + h * 64 + dsb, vcol = 2048 + h * 64 + dsb;
  for (int sc = 0; sc < 8; ++sc) {
    __syncthreads();
    const size_t roff = base + (size_t)(sc * 32 + tt) * 3072;
    uint4 kb = *(const uint4*)(qkv + roff + kcol);
    uint4 vb = *(const uint4*)(qkv + roff + vcol);
    const unsigned int* kw = (const unsigned int*)&kb;
    const unsigned int* vw = (const unsigned int*)&vb;
#pragma unroll
    for (int w2 = 0; w2 < 4; ++w2) {
      float k0 = bf2f((unsigned short)(kw[w2] & 0xffffu));
      float k1 = bf2f((unsigned short)(kw[w2] >> 16));
      ks[tt][dsb + 2 * w2]     = (k0 > 0.f) ? k0 + 1.f : expf(k0);  // elu(k)+1
      ks[tt][dsb + 2 * w2 + 1] = (k1 > 0.f) ? k1 + 1.f : expf(k1);
      vs[tt][dsb + 2 * w2]     = bf2f((unsigned short)(vw[w2] & 0xffffu));
      vs[tt][dsb + 2 * w2 + 1] = bf2f((unsigned short)(vw[w2] >> 16));
    }
    __syncthreads();
#pragma unroll 4
    for (int t2 = 0; t2 < 32; ++t2) {
      float vv = vs[t2][m];
#pragma unroll
      for (int j = 0; j < 16; ++j) acc[j] += ks[t2][wid * 16 + j] * vv;  // broadcast read
      if (tid < 64) ksacc += ks[t2][tid];
    }
  }
  float* dst = kvp + (size_t)(tc * 128 + bh) * 4096;
#pragma unroll
  for (int j = 0; j < 16; ++j) dst[(wid * 16 + j) * 64 + m] = acc[j];
  if (tid < 64) ksump[(size_t)(tc * 128 + bh) * 64 + tid] = ksacc;
}

__global__ __launch_bounds__(256) void attn_kv_reduce(const float* __restrict__ kvp,
                                                      const float* __restrict__ ksump,
                                                      float* __restrict__ kvf,
                                                      float* __restrict__ ksumf) {
  const int bh = blockIdx.x;
  const int tid = threadIdx.x;
  for (int i = tid; i < 4096; i += 256) {
    float s = 0.f;
#pragma unroll
    for (int tc = 0; tc < 8; ++tc) s += kvp[(size_t)(tc * 128 + bh) * 4096 + i];
    kvf[(size_t)bh * 4096 + i] = s;
  }
  if (tid < 64) {
    float s = 0.f;
#pragma unroll
    for (int tc = 0; tc < 8; ++tc) s += ksump[(size_t)(tc * 128 + bh) * 64 + tid];
    ksumf[bh * 64 + tid] = s;
  }
}

// phase B: out[t,m] = (sum_d qp[d]*kv[d][m]) / (qp . ksum + eps); 4 t-rows per pass
__global__ __launch_bounds__(256) void attn_out_k(const unsigned short* __restrict__ qkv,
                                                  const float* __restrict__ kvf,
                                                  const float* __restrict__ ksumf,
                                                  unsigned short* __restrict__ qkvO) {
  const int bh = blockIdx.x, tcb = blockIdx.y;
  const int b = bh >> 4, h = bh & 15;
  const int tid = threadIdx.x, wid = tid >> 6, lane = tid & 63;
  __shared__ float kvs[4096];
  __shared__ float kss[64];
  __shared__ float qps[4][4][64];
  for (int i = tid; i < 1024; i += 256)
    ((float4*)kvs)[i] = ((const float4*)(kvf + (size_t)bh * 4096))[i];
  if (tid < 64) kss[tid] = ksumf[bh * 64 + tid];
  __syncthreads();
  for (int it = 0; it < 64; it += 4) {
    float zr[4];
#pragma unroll
    for (int r = 0; r < 4; ++r) {
      const int t = tcb * 256 + wid * 64 + it + r;
      const size_t row = (size_t)b * TSEQ + t;
      float qv = bf2f(qkv[row * 3072 + h * 64 + lane]);
      float qp = (qv > 0.f) ? qv + 1.f : expf(qv);
      float rs = qp * kss[lane];
#pragma unroll
      for (int o = 32; o; o >>= 1) rs += __shfl_xor(rs, o);
      zr[r] = 1.0f / (rs + 1e-6f);
      qps[wid][r][lane] = qp;
    }
    float o0 = 0.f, o1 = 0.f, o2 = 0.f, o3 = 0.f;
#pragma unroll 8
    for (int d = 0; d < 64; ++d) {
      const float kvv = kvs[d * 64 + lane];
      o0 += qps[wid][0][d] * kvv;
      o1 += qps[wid][1][d] * kvv;
      o2 += qps[wid][2][d] * kvv;
      o3 += qps[wid][3][d] * kvv;
    }
    const size_t row0 = (size_t)b * TSEQ + tcb * 256 + wid * 64 + it;
    qkvO[(row0 + 0) * 3072 + h * 64 + lane] = f2bf(o0 * zr[0]);
    qkvO[(row0 + 1) * 3072 + h * 64 + lane] = f2bf(o1 * zr[1]);
    qkvO[(row0 + 2) * 3072 + h * 64 + lane] = f2bf(o2 * zr[2]);
    qkvO[(row0 + 3) * 3072 + h * 64 + lane] = f2bf(o3 * zr[3]);
  }
}

// ---------- launch ----------
extern "C" void kernel_launch(void* const* d_in, const int* in_sizes, int n_in,
                              void* d_out, int out_size, void* d_ws, size_t ws_size,
                              hipStream_t stream) {
  const float* x_in = (const float*)d_in[0];
  const float* Wq = (const float*)d_in[1];
  const float* bq = (const float*)d_in[2];
  const float* Wk = (const float*)d_in[3];
  const float* bk = (const float*)d_in[4];
  const float* Wv = (const float*)d_in[5];
  const float* bv = (const float*)d_in[6];
  const float* Wo = (const float*)d_in[7];
  const float* bo = (const float*)d_in[8];
  const float* W1 = (const float*)d_in[9];
  const float* b1 = (const float*)d_in[10];
  const float* W2 = (const float*)d_in[11];
  const float* b2 = (const float*)d_in[12];
  const float* ln1s = (const float*)d_in[13];
  const float* ln1b = (const float*)d_in[14];
  const float* ln2s = (const float*)d_in[15];
  const float* ln2b = (const float*)d_in[16];
  const float* lnfs = (const float*)d_in[17];
  const float* lnfb = (const float*)d_in[18];

  // Residual x lives in d_out (NROWS*DMOD f32); final addln<1> writes LN result in-place.
  float* x = (float*)d_out;

  // Workspace layout (~202.3 MiB):
  char* w = (char*)d_ws;
  unsigned short* hh    = (unsigned short*)(w + 0);           //  32 MB bf16 LN out / y
  unsigned short* qkv   = (unsigned short*)(w + 33554432);    //  96 MB bf16 q|k|v
  unsigned short* h1    = (unsigned short*)(w + 33554432);    // 128 MB bf16 FFN mid (aliases qkv)
  unsigned short* qkvwt = (unsigned short*)(w + 167772160);   //   6 MB per-layer Wqkv^T
  unsigned short* wot   = (unsigned short*)(w + 174063616);   //   2 MB per-layer Wo^T
  unsigned short* w1t   = (unsigned short*)(w + 176160768);   //   8 MB per-layer W1^T
  unsigned short* w2t   = (unsigned short*)(w + 184549376);   //   8 MB per-layer W2^T
  float*          bqkv  = (float*)(w + 192937984);            //  48 KB
  float*          kvp   = (float*)(w + 192987136);            //  16 MB
  float*          ksump = (float*)(w + 209764352);            // 256 KB
  float*          kvf   = (float*)(w + 210026496);            //   2 MB
  float*          ksumf = (float*)(w + 212123648);            //  32 KB
  (void)ws_size; (void)in_sizes; (void)n_in; (void)out_size;

  dim3 b256(256);
  dim3 b512(512);
  dim3 tb(32, 8);
  concat_bias<<<48, b256, 0, stream>>>(bq, bk, bv, bqkv);
  embedln_k<<<NROWS, b256, 0, stream>>>(x_in, ln1s, ln1b, x, hh);

  for (int l = 0; l < 4; ++l) {
    transpose_cvt<<<dim3(32, 32), tb, 0, stream>>>(Wq + (size_t)l * 1048576, qkvwt,           1024, 1024);
    transpose_cvt<<<dim3(32, 32), tb, 0, stream>>>(Wk + (size_t)l * 1048576, qkvwt + 1048576, 1024, 1024);
    transpose_cvt<<<dim3(32, 32), tb, 0, stream>>>(Wv + (size_t)l * 1048576, qkvwt + 2097152, 1024, 1024);
    transpose_cvt<<<dim3(32, 32), tb, 0, stream>>>(Wo + (size_t)l * 1048576, wot, 1024, 1024);
    transpose_cvt<<<dim3(128, 32), tb, 0, stream>>>(W1 + (size_t)l * 4194304, w1t, 1024, 4096);
    transpose_cvt<<<dim3(32, 128), tb, 0, stream>>>(W2 + (size_t)l * 4194304, w2t, 4096, 1024);

    // QKV projection (reads hh = LN1 output)
    gemm256<0><<<dim3(64 * 12), b512, 0, stream>>>(hh, qkvwt, bqkv + l * 3072, qkv,
                                                   NROWS, 3072, 1024, 1024);
    attn_kv_partial<<<dim3(128, 8), b256, 0, stream>>>(qkv, kvp, ksump);
    attn_kv_reduce<<<128, b256, 0, stream>>>(kvp, ksump, kvf, ksumf);
    attn_out_k<<<dim3(128, 8), b256, 0, stream>>>(qkv, kvf, ksumf, qkv);
    // Wo: A = attn output in q-slice of qkv (lda 3072); y -> hh (dead after QKV gemm)
    gemm256<0><<<dim3(64 * 4), b512, 0, stream>>>(qkv, wot, bo + l * 1024, hh,
                                                  NROWS, 1024, 1024, 3072);
    addln_k<0><<<NROWS, b256, 0, stream>>>(x, hh, ln2s + l * 1024, ln2b + l * 1024, hh, nullptr);
    // FFN
    gemm256<1><<<dim3(64 * 16), b512, 0, stream>>>(hh, w1t, b1 + l * 4096, h1,
                                                   NROWS, 4096, 1024, 1024);
    gemm256<0><<<dim3(64 * 4), b512, 0, stream>>>(h1, w2t, b2 + l * 1024, hh,
                                                  NROWS, 1024, 4096, 4096);
    if (l < 3)
      addln_k<0><<<NROWS, b256, 0, stream>>>(x, hh, ln1s + (l + 1) * 1024, ln1b + (l + 1) * 1024,
                                             hh, nullptr);
    else
      addln_k<1><<<NROWS, b256, 0, stream>>>(x, hh, lnfs, lnfb, nullptr, x);
  }
}